// Round 1
// baseline (187.317 us; speedup 1.0000x reference)
//
#include <hip/hip_runtime.h>
#include <hip/hip_bf16.h>
#include <stdint.h>

// out[4096,4096] = x[4096,2048] @ matrix[0,4096,2048]^T   (fp32 in/out)
// Strategy: fp32 -> bf16 cast pass into d_ws, then m97-style bf16 MFMA GEMM
// (128x128 tile, BK=32, global_load_lds width=16, 16x16x32 MFMA).

#define GAS __attribute__((address_space(1)))
#define LAS __attribute__((address_space(3)))

typedef __bf16 bf16x8 __attribute__((ext_vector_type(8)));
typedef float f32x4 __attribute__((ext_vector_type(4)));

static __device__ __forceinline__ unsigned short f2bf(float f) {
  union { float f; uint32_t u; } a; a.f = f;
  uint32_t u = a.u;
  u += 0x7FFFu + ((u >> 16) & 1u);   // round-to-nearest-even
  return (unsigned short)(u >> 16);
}

// Both tensors are 4096*2048 = 8388608 elements; grid.y picks which one.
__global__ void cvt_f32_to_bf16(const float4* __restrict__ x,
                                const float4* __restrict__ m,
                                ushort4* __restrict__ xo,
                                ushort4* __restrict__ mo) {
  const int i = blockIdx.x * blockDim.x + threadIdx.x;   // 0 .. 2M-1 (float4s)
  const float4* __restrict__ src = blockIdx.y ? m : x;
  ushort4* __restrict__ dst      = blockIdx.y ? mo : xo;
  float4 v = src[i];
  ushort4 o;
  o.x = f2bf(v.x); o.y = f2bf(v.y); o.z = f2bf(v.z); o.w = f2bf(v.w);
  dst[i] = o;
}

// C[M,N] = A[M,K] * B[N,K]^T,  M=N=4096 (M=B rows of x, N=rows of matrix), K=2048
// block = 256 threads (4 waves), tile 128x128, BK=32.
// Wave w: quadrant (wm,wn) = (w&1, w>>1), 4x4 sub-tiles of 16x16.
__global__ void gemm_bt_bf16(const unsigned short* __restrict__ A,
                             const unsigned short* __restrict__ B,
                             float* __restrict__ C) {
  constexpr int K = 2048;
  constexpr int N = 4096;

  __shared__ unsigned short As[128 * 32];   // [row][k], 64 B per row
  __shared__ unsigned short Bs[128 * 32];

  const int tid  = threadIdx.x;
  const int wave = tid >> 6;
  const int lane = tid & 63;
  const int wm   = wave & 1;
  const int wn   = wave >> 1;
  const int bM   = blockIdx.y * 128;
  const int bN   = blockIdx.x * 128;

  const int quad = lane >> 4;   // 0..3 : k-group for fragments, row-group for C
  const int l15  = lane & 15;

  // Staging: each global_load_lds stages 1024 B per wave = 16 rows x 64 B.
  // Lane i covers LDS offset i*16 B => row = lane>>2, 16B-group = lane&3.
  const int srow = lane >> 2;   // 0..15
  const int skg  = lane & 3;    // 0..3
  const int s0 = wave * 2;      // this wave's two 16-row segments (of 8)
  const int s1 = s0 + 1;

  const size_t aOff0 = (size_t)(bM + s0 * 16 + srow) * K + skg * 8;
  const size_t aOff1 = (size_t)(bM + s1 * 16 + srow) * K + skg * 8;
  const size_t bOff0 = (size_t)(bN + s0 * 16 + srow) * K + skg * 8;
  const size_t bOff1 = (size_t)(bN + s1 * 16 + srow) * K + skg * 8;

  f32x4 acc[4][4] = {};

  for (int k0 = 0; k0 < K; k0 += 32) {
    // ---- stage A,B tiles: global -> LDS, 16 B/lane direct DMA ----
    __builtin_amdgcn_global_load_lds((const GAS void*)(A + aOff0 + k0),
                                     (LAS void*)(As + s0 * 512), 16, 0, 0);
    __builtin_amdgcn_global_load_lds((const GAS void*)(A + aOff1 + k0),
                                     (LAS void*)(As + s1 * 512), 16, 0, 0);
    __builtin_amdgcn_global_load_lds((const GAS void*)(B + bOff0 + k0),
                                     (LAS void*)(Bs + s0 * 512), 16, 0, 0);
    __builtin_amdgcn_global_load_lds((const GAS void*)(B + bOff1 + k0),
                                     (LAS void*)(Bs + s1 * 512), 16, 0, 0);
    __syncthreads();

    // ---- fragments: lane holds 8 contiguous k at row (lane&15), k-group quad ----
    bf16x8 af[4], bfr[4];
#pragma unroll
    for (int i = 0; i < 4; ++i) {
      const int m = wm * 64 + i * 16 + l15;
      af[i] = *(const bf16x8*)(As + m * 32 + quad * 8);
      const int n = wn * 64 + i * 16 + l15;
      bfr[i] = *(const bf16x8*)(Bs + n * 32 + quad * 8);
    }

#pragma unroll
    for (int i = 0; i < 4; ++i)
#pragma unroll
      for (int j = 0; j < 4; ++j)
        acc[i][j] = __builtin_amdgcn_mfma_f32_16x16x32_bf16(af[i], bfr[j],
                                                            acc[i][j], 0, 0, 0);
    __syncthreads();
  }

  // ---- epilogue: C/D layout col=lane&15, row=quad*4+reg ----
#pragma unroll
  for (int i = 0; i < 4; ++i) {
    const int row0 = bM + wm * 64 + i * 16 + quad * 4;
#pragma unroll
    for (int j = 0; j < 4; ++j) {
      const int col = bN + wn * 64 + j * 16 + l15;
#pragma unroll
      for (int t = 0; t < 4; ++t)
        C[(size_t)(row0 + t) * N + col] = acc[i][j][t];
    }
  }
}

extern "C" void kernel_launch(void* const* d_in, const int* in_sizes, int n_in,
                              void* d_out, int out_size, void* d_ws, size_t ws_size,
                              hipStream_t stream) {
  const float* x   = (const float*)d_in[0];   // [4096, 2048]
  const float* mat = (const float*)d_in[1];   // [1, 4096, 2048]
  float* out = (float*)d_out;                 // [4096, 4096]

  constexpr size_t ELEMS = 4096ull * 2048ull;      // per tensor
  unsigned short* xb = (unsigned short*)d_ws;      // bf16 x
  unsigned short* mb = xb + ELEMS;                 // bf16 matrix

  // cast pass: 2M float4 per tensor, 256 thr/block
  dim3 cgrid((unsigned)(ELEMS / 4 / 256), 2);
  cvt_f32_to_bf16<<<cgrid, 256, 0, stream>>>((const float4*)x, (const float4*)mat,
                                             (ushort4*)xb, (ushort4*)mb);

  // GEMM: 32x32 blocks of 128x128 tiles
  gemm_bt_bf16<<<dim3(32, 32), 256, 0, stream>>>(xb, mb, out);
}

// Round 2
// 171.968 us; speedup vs baseline: 1.0893x; 1.0893x over previous
//
#include <hip/hip_runtime.h>
#include <hip/hip_bf16.h>
#include <stdint.h>

// out[4096,4096] = x[4096,2048] @ matrix[0,4096,2048]^T   (fp32 in/out)
// R2: fp32->bf16 cast pass, then bf16 MFMA GEMM with BK=64 (half the barrier
// drains per K vs BK=32) + XOR-swizzled LDS chunks (128B row stride would be
// 16-way bank-conflicted otherwise). 128x128 tile, global_load_lds width=16,
// 16x16x32 MFMA, 4 waves x (64x64 quadrant, 4x4 frags).

#define GAS __attribute__((address_space(1)))
#define LAS __attribute__((address_space(3)))

typedef __bf16 bf16x8 __attribute__((ext_vector_type(8)));
typedef float f32x4 __attribute__((ext_vector_type(4)));

static __device__ __forceinline__ unsigned short f2bf(float f) {
  union { float f; uint32_t u; } a; a.f = f;
  uint32_t u = a.u;
  u += 0x7FFFu + ((u >> 16) & 1u);   // round-to-nearest-even
  return (unsigned short)(u >> 16);
}

// Both tensors are 4096*2048 = 8388608 elements; grid.y picks which one.
__global__ void cvt_f32_to_bf16(const float4* __restrict__ x,
                                const float4* __restrict__ m,
                                ushort4* __restrict__ xo,
                                ushort4* __restrict__ mo) {
  const int i = blockIdx.x * blockDim.x + threadIdx.x;   // 0 .. 2M-1 (float4s)
  const float4* __restrict__ src = blockIdx.y ? m : x;
  ushort4* __restrict__ dst      = blockIdx.y ? mo : xo;
  float4 v = src[i];
  ushort4 o;
  o.x = f2bf(v.x); o.y = f2bf(v.y); o.z = f2bf(v.z); o.w = f2bf(v.w);
  dst[i] = o;
}

// C[M,N] = A[M,K] * B[N,K]^T, M=N=4096, K=2048. block=256 (4 waves),
// tile 128x128, BK=64. LDS row = 64 elems (128B) stored as 8 chunks of
// 8 elems; global chunk c of row r lives at physical chunk c^(r&7).
__global__ __launch_bounds__(256, 4)
void gemm_bt_bf16(const unsigned short* __restrict__ A,
                  const unsigned short* __restrict__ B,
                  float* __restrict__ C) {
  constexpr int K = 2048;
  constexpr int N = 4096;

  __shared__ unsigned short As[128 * 64];   // 16 KB
  __shared__ unsigned short Bs[128 * 64];   // 16 KB

  const int tid  = threadIdx.x;
  const int wave = tid >> 6;
  const int lane = tid & 63;
  const int wm   = wave & 1;
  const int wn   = wave >> 1;
  const int bM   = blockIdx.y * 128;
  const int bN   = blockIdx.x * 128;

  const int quad = lane >> 4;   // 0..3
  const int l15  = lane & 15;
  const int mx   = l15 & 7;     // row&7 for swizzle (row = ..+l15, mults of 8)

  // Staging: per wave, inst t covers rows wave*32 + t*8 + (lane>>3),
  // global 8-elem chunk (lane&7)^(lane>>3)  (XOR swizzle via source permute,
  // since the DMA's LDS scatter is fixed at base + lane*16B).
  const int lr = lane >> 3;            // 0..7
  const int lc = (lane & 7) ^ lr;      // swizzled source chunk
  const size_t aBase = (size_t)(bM + wave * 32 + lr) * K + lc * 8;
  const size_t bBase = (size_t)(bN + wave * 32 + lr) * K + lc * 8;
  const int ldsBase = wave * 32 * 64;  // elems; + t*512 per instruction

  f32x4 acc[4][4] = {};

  for (int k0 = 0; k0 < K; k0 += 64) {
#pragma unroll
    for (int t = 0; t < 4; ++t) {
      __builtin_amdgcn_global_load_lds((const GAS void*)(A + aBase + k0 + t * 8 * K),
                                       (LAS void*)(As + ldsBase + t * 512), 16, 0, 0);
      __builtin_amdgcn_global_load_lds((const GAS void*)(B + bBase + k0 + t * 8 * K),
                                       (LAS void*)(Bs + ldsBase + t * 512), 16, 0, 0);
    }
    __syncthreads();

#pragma unroll
    for (int ks = 0; ks < 2; ++ks) {
      bf16x8 af[4], bfr[4];
#pragma unroll
      for (int i = 0; i < 4; ++i) {
        const int m = wm * 64 + i * 16 + l15;
        af[i]  = *(const bf16x8*)(As + m * 64 + (((ks * 4 + quad) ^ mx) << 3));
        const int n = wn * 64 + i * 16 + l15;
        bfr[i] = *(const bf16x8*)(Bs + n * 64 + (((ks * 4 + quad) ^ mx) << 3));
      }
#pragma unroll
      for (int i = 0; i < 4; ++i)
#pragma unroll
        for (int j = 0; j < 4; ++j)
          acc[i][j] = __builtin_amdgcn_mfma_f32_16x16x32_bf16(af[i], bfr[j],
                                                              acc[i][j], 0, 0, 0);
    }
    __syncthreads();
  }

  // Epilogue: C/D layout col=lane&15, row=quad*4+reg (m89-verified).
#pragma unroll
  for (int i = 0; i < 4; ++i) {
    const int row0 = bM + wm * 64 + i * 16 + quad * 4;
#pragma unroll
    for (int j = 0; j < 4; ++j) {
      const int col = bN + wn * 64 + j * 16 + l15;
#pragma unroll
      for (int t = 0; t < 4; ++t)
        C[(size_t)(row0 + t) * N + col] = acc[i][j][t];
    }
  }
}

extern "C" void kernel_launch(void* const* d_in, const int* in_sizes, int n_in,
                              void* d_out, int out_size, void* d_ws, size_t ws_size,
                              hipStream_t stream) {
  const float* x   = (const float*)d_in[0];   // [4096, 2048]
  const float* mat = (const float*)d_in[1];   // [1, 4096, 2048]
  float* out = (float*)d_out;                 // [4096, 4096]

  constexpr size_t ELEMS = 4096ull * 2048ull;      // per tensor
  unsigned short* xb = (unsigned short*)d_ws;      // bf16 x
  unsigned short* mb = xb + ELEMS;                 // bf16 matrix

  dim3 cgrid((unsigned)(ELEMS / 4 / 256), 2);
  cvt_f32_to_bf16<<<cgrid, 256, 0, stream>>>((const float4*)x, (const float4*)mat,
                                             (ushort4*)xb, (ushort4*)mb);

  gemm_bt_bf16<<<dim3(32, 32), 256, 0, stream>>>(xb, mb, out);
}

// Round 3
// 170.508 us; speedup vs baseline: 1.0986x; 1.0086x over previous
//
#include <hip/hip_runtime.h>
#include <hip/hip_bf16.h>
#include <stdint.h>

// out[4096,4096] = x[4096,2048] @ matrix[0,4096,2048]^T   (fp32 in/out)
// R3: cast pass unchanged. GEMM: block tile 256x128 (4 waves, each 128x64 as
// 8x4 frags of 16x16x32), BK=64, XOR-swizzled LDS. Rationale: R2 was LDS-BW
// bound; (r+c)/(r*c) read ratio 0.5 -> 0.375 and staging writes -25%.
// 2 blocks/CU (regs ~200, LDS 48KB) -- MFMA/barrier doubles to compensate.

#define GAS __attribute__((address_space(1)))
#define LAS __attribute__((address_space(3)))

typedef __bf16 bf16x8 __attribute__((ext_vector_type(8)));
typedef float f32x4 __attribute__((ext_vector_type(4)));

static __device__ __forceinline__ unsigned short f2bf(float f) {
  union { float f; uint32_t u; } a; a.f = f;
  uint32_t u = a.u;
  u += 0x7FFFu + ((u >> 16) & 1u);   // round-to-nearest-even
  return (unsigned short)(u >> 16);
}

__global__ void cvt_f32_to_bf16(const float4* __restrict__ x,
                                const float4* __restrict__ m,
                                ushort4* __restrict__ xo,
                                ushort4* __restrict__ mo) {
  const int i = blockIdx.x * blockDim.x + threadIdx.x;
  const float4* __restrict__ src = blockIdx.y ? m : x;
  ushort4* __restrict__ dst      = blockIdx.y ? mo : xo;
  float4 v = src[i];
  ushort4 o;
  o.x = f2bf(v.x); o.y = f2bf(v.y); o.z = f2bf(v.z); o.w = f2bf(v.w);
  dst[i] = o;
}

// C[M,N] = A[M,K]*B[N,K]^T, M=N=4096, K=2048. 256 threads = 4 waves.
// Block tile 256x128; wave (wm=wave&1, wn=wave>>1) owns rows wm*128..+128,
// cols wn*64..+64 as acc[8][4] of 16x16. BK=64; LDS row = 8 chunks of 8
// elems, global chunk c of row r at physical chunk c^(r&7).
__global__ __launch_bounds__(256, 2)
void gemm_bt_bf16(const unsigned short* __restrict__ A,
                  const unsigned short* __restrict__ B,
                  float* __restrict__ C) {
  constexpr int K = 2048;
  constexpr int N = 4096;

  __shared__ unsigned short As[256 * 64];   // 32 KB
  __shared__ unsigned short Bs[128 * 64];   // 16 KB

  const int tid  = threadIdx.x;
  const int wave = tid >> 6;
  const int lane = tid & 63;
  const int wm   = wave & 1;
  const int wn   = wave >> 1;
  const int bM   = blockIdx.y * 256;
  const int bN   = blockIdx.x * 128;

  const int quad = lane >> 4;   // 0..3
  const int l15  = lane & 15;
  const int mx   = l15 & 7;     // = row&7 for all fragment rows (offsets are x8)

  // Staging (per wave): A rows [wave*64, wave*64+64) in 8 insts of 8 rows,
  // B rows [wave*32, wave*32+32) in 4 insts. Each inst: 64 lanes x 16B =
  // 8 rows x 128B. lane covers row lr=lane>>3, swizzled source chunk lc.
  const int lr = lane >> 3;
  const int lc = (lane & 7) ^ lr;
  const size_t aBase = (size_t)(bM + wave * 64 + lr) * K + lc * 8;
  const size_t bBase = (size_t)(bN + wave * 32 + lr) * K + lc * 8;
  const int aLds = wave * 64 * 64;   // elems
  const int bLds = wave * 32 * 64;

  f32x4 acc[8][4] = {};

  for (int k0 = 0; k0 < K; k0 += 64) {
#pragma unroll
    for (int t = 0; t < 8; ++t)
      __builtin_amdgcn_global_load_lds((const GAS void*)(A + aBase + k0 + t * 8 * K),
                                       (LAS void*)(As + aLds + t * 512), 16, 0, 0);
#pragma unroll
    for (int t = 0; t < 4; ++t)
      __builtin_amdgcn_global_load_lds((const GAS void*)(B + bBase + k0 + t * 8 * K),
                                       (LAS void*)(Bs + bLds + t * 512), 16, 0, 0);
    __syncthreads();

#pragma unroll
    for (int ks = 0; ks < 2; ++ks) {
      const int koff = ((ks * 4 + quad) ^ mx) << 3;   // note: ^mx applies to
      // the chunk index; (ks*4+quad) in 0..7, mx in 0..7 -> ok.
      bf16x8 af[8], bfr[4];
#pragma unroll
      for (int i = 0; i < 8; ++i) {
        const int m = wm * 128 + i * 16 + l15;
        af[i] = *(const bf16x8*)(As + m * 64 + koff);
      }
#pragma unroll
      for (int j = 0; j < 4; ++j) {
        const int n = wn * 64 + j * 16 + l15;
        bfr[j] = *(const bf16x8*)(Bs + n * 64 + koff);
      }
#pragma unroll
      for (int i = 0; i < 8; ++i)
#pragma unroll
        for (int j = 0; j < 4; ++j)
          acc[i][j] = __builtin_amdgcn_mfma_f32_16x16x32_bf16(af[i], bfr[j],
                                                              acc[i][j], 0, 0, 0);
    }
    __syncthreads();
  }

  // Epilogue: C/D layout col=lane&15, row=quad*4+reg (m89-verified).
#pragma unroll
  for (int i = 0; i < 8; ++i) {
    const int row0 = bM + wm * 128 + i * 16 + quad * 4;
#pragma unroll
    for (int j = 0; j < 4; ++j) {
      const int col = bN + wn * 64 + j * 16 + l15;
#pragma unroll
      for (int t = 0; t < 4; ++t)
        C[(size_t)(row0 + t) * N + col] = acc[i][j][t];
    }
  }
}

extern "C" void kernel_launch(void* const* d_in, const int* in_sizes, int n_in,
                              void* d_out, int out_size, void* d_ws, size_t ws_size,
                              hipStream_t stream) {
  const float* x   = (const float*)d_in[0];   // [4096, 2048]
  const float* mat = (const float*)d_in[1];   // [1, 4096, 2048]
  float* out = (float*)d_out;                 // [4096, 4096]

  constexpr size_t ELEMS = 4096ull * 2048ull;
  unsigned short* xb = (unsigned short*)d_ws;
  unsigned short* mb = xb + ELEMS;

  dim3 cgrid((unsigned)(ELEMS / 4 / 256), 2);
  cvt_f32_to_bf16<<<cgrid, 256, 0, stream>>>((const float4*)x, (const float4*)mat,
                                             (ushort4*)xb, (ushort4*)mb);

  // 512 blocks: grid.x = N/128 = 32, grid.y = M/256 = 16 -> 2 blocks/CU
  gemm_bt_bf16<<<dim3(32, 16), 256, 0, stream>>>(xb, mb, out);
}